// Round 1
// baseline (92.306 us; speedup 1.0000x reference)
//
#include <hip/hip_runtime.h>

// Problem: B=32, T=2048, D=1024 (fp32)
// out[b,d] = sum_t softmax_t(tanh(x[b,t,:]·W + bias[t])) * x[b,t,d]

__global__ __launch_bounds__(256) void score_kernel(
    const float* __restrict__ x, const float* __restrict__ w,
    const float* __restrict__ bias, float* __restrict__ scores,
    int T, int nrows)
{
    // one wave (64 lanes) per row of length D=1024
    int wave = threadIdx.x >> 6;
    int lane = threadIdx.x & 63;
    int row = blockIdx.x * 4 + wave;
    if (row >= nrows) return;
    const float4* x4 = (const float4*)x + (size_t)row * 256;  // D/4 = 256
    const float4* w4 = (const float4*)w;
    float acc = 0.f;
#pragma unroll
    for (int k = 0; k < 4; ++k) {
        float4 a = x4[lane + k * 64];
        float4 b = w4[lane + k * 64];
        acc += a.x * b.x + a.y * b.y + a.z * b.z + a.w * b.w;
    }
#pragma unroll
    for (int off = 32; off >= 1; off >>= 1)
        acc += __shfl_down(acc, off);
    if (lane == 0) {
        int t = row % T;
        scores[row] = tanhf(acc + bias[t]);
    }
}

__global__ __launch_bounds__(256) void softmax_kernel(
    const float* __restrict__ scores, float* __restrict__ weights, int T)
{
    // one block per batch; T=2048, 256 threads -> 8 elems/thread
    int b = blockIdx.x;
    int tid = threadIdx.x;
    const float* s = scores + (size_t)b * T;
    float* wgt = weights + (size_t)b * T;

    float v[8];
    float m = -1e30f;
#pragma unroll
    for (int i = 0; i < 8; ++i) {
        v[i] = s[tid + i * 256];
        m = fmaxf(m, v[i]);
    }
    __shared__ float redm[4];
    __shared__ float reds[4];
#pragma unroll
    for (int off = 32; off >= 1; off >>= 1)
        m = fmaxf(m, __shfl_down(m, off));
    if ((tid & 63) == 0) redm[tid >> 6] = m;
    __syncthreads();
    m = fmaxf(fmaxf(redm[0], redm[1]), fmaxf(redm[2], redm[3]));

    float sum = 0.f;
#pragma unroll
    for (int i = 0; i < 8; ++i) {
        v[i] = __expf(v[i] - m);
        sum += v[i];
    }
#pragma unroll
    for (int off = 32; off >= 1; off >>= 1)
        sum += __shfl_down(sum, off);
    if ((tid & 63) == 0) reds[tid >> 6] = sum;
    __syncthreads();
    sum = (reds[0] + reds[1]) + (reds[2] + reds[3]);
    float inv = 1.0f / sum;
#pragma unroll
    for (int i = 0; i < 8; ++i)
        wgt[tid + i * 256] = v[i] * inv;
}

__global__ __launch_bounds__(256) void pool_kernel(
    const float* __restrict__ x, const float* __restrict__ weights,
    float* __restrict__ out, int T)
{
    // block handles (b, chunk of 64 t-rows); 256 threads cover D=1024 as float4
    int b = blockIdx.y;
    int c = blockIdx.x;
    int tid = threadIdx.x;
    int t0 = c * 64;

    __shared__ float wl[64];
    if (tid < 64) wl[tid] = weights[(size_t)b * T + t0 + tid];
    __syncthreads();

    const float4* x4 = (const float4*)x + ((size_t)b * T + t0) * 256;
    float4 acc = {0.f, 0.f, 0.f, 0.f};
    for (int tt = 0; tt < 64; ++tt) {
        float wv = wl[tt];
        float4 a = x4[(size_t)tt * 256 + tid];
        acc.x += wv * a.x;
        acc.y += wv * a.y;
        acc.z += wv * a.z;
        acc.w += wv * a.w;
    }
    float* o = out + (size_t)b * 1024 + tid * 4;
    atomicAdd(o + 0, acc.x);
    atomicAdd(o + 1, acc.y);
    atomicAdd(o + 2, acc.z);
    atomicAdd(o + 3, acc.w);
}

extern "C" void kernel_launch(void* const* d_in, const int* in_sizes, int n_in,
                              void* d_out, int out_size, void* d_ws, size_t ws_size,
                              hipStream_t stream) {
    const float* x    = (const float*)d_in[0];   // [B,T,D]
    const float* w    = (const float*)d_in[1];   // [D,1]
    const float* bias = (const float*)d_in[2];   // [T,1]
    float* out = (float*)d_out;

    int D = in_sizes[1];            // 1024
    int T = in_sizes[2];            // 2048
    int nrows = in_sizes[0] / D;    // B*T = 65536
    int B = nrows / T;              // 32

    float* scores  = (float*)d_ws;          // B*T floats
    float* weights = scores + nrows;        // B*T floats

    hipMemsetAsync(d_out, 0, (size_t)out_size * sizeof(float), stream);
    score_kernel<<<(nrows + 3) / 4, 256, 0, stream>>>(x, w, bias, scores, T, nrows);
    softmax_kernel<<<B, 256, 0, stream>>>(scores, weights, T);
    pool_kernel<<<dim3(T / 64, B), 256, 0, stream>>>(x, weights, out, T);
}

// Round 2
// 59.174 us; speedup vs baseline: 1.5599x; 1.5599x over previous
//
#include <hip/hip_runtime.h>

// B=32, T=2048, D=1024 (fp32)
// out[b,d] = sum_t softmax_t(tanh(x[b,t,:]·W + bias[t])) * x[b,t,d]
// tanh output is in (-1,1) -> softmax needs no max subtraction -> single-pass fusion.

#define PSTR 1032  // partial stride in floats: [0]=l_sum, [8..1032)=acc[1024] (16B aligned)

__global__ __launch_bounds__(256) void fused_score_pool(
    const float* __restrict__ x, const float* __restrict__ w,
    const float* __restrict__ bias, float* __restrict__ partials,
    int T, int C)
{
    const int c = blockIdx.x;      // T-chunk
    const int b = blockIdx.y;      // batch
    const int wv = threadIdx.x >> 6;
    const int lane = threadIdx.x & 63;

    const int rows = T / C;        // rows per chunk (multiple of 16, enforced on host)
    const int r0 = c * rows;
    const int rend = r0 + rows;

    // W fragment: lane l holds w[k*256 + l*4 .. +3] for k=0..3
    const float4* w4 = (const float4*)w;
    const float4 wf0 = w4[lane];
    const float4 wf1 = w4[lane + 64];
    const float4 wf2 = w4[lane + 128];
    const float4 wf3 = w4[lane + 192];

    const float4* xb = (const float4*)x + (size_t)b * T * 256;

    float4 acc0 = {0.f,0.f,0.f,0.f}, acc1 = {0.f,0.f,0.f,0.f};
    float4 acc2 = {0.f,0.f,0.f,0.f}, acc3 = {0.f,0.f,0.f,0.f};
    float lsum = 0.f;

    // each wave: 4 consecutive rows per iteration, 4 waves stride 16 rows
    for (int base = r0 + wv * 4; base + 4 <= rend; base += 16) {
        float4 a[4][4];
#pragma unroll
        for (int j = 0; j < 4; ++j) {
            const float4* xr = xb + (size_t)(base + j) * 256;
            a[j][0] = xr[lane];
            a[j][1] = xr[lane + 64];
            a[j][2] = xr[lane + 128];
            a[j][3] = xr[lane + 192];
        }
#pragma unroll
        for (int j = 0; j < 4; ++j) {
            float d = a[j][0].x*wf0.x + a[j][0].y*wf0.y + a[j][0].z*wf0.z + a[j][0].w*wf0.w;
            d += a[j][1].x*wf1.x + a[j][1].y*wf1.y + a[j][1].z*wf1.z + a[j][1].w*wf1.w;
            d += a[j][2].x*wf2.x + a[j][2].y*wf2.y + a[j][2].z*wf2.z + a[j][2].w*wf2.w;
            d += a[j][3].x*wf3.x + a[j][3].y*wf3.y + a[j][3].z*wf3.z + a[j][3].w*wf3.w;
#pragma unroll
            for (int off = 1; off < 64; off <<= 1)
                d += __shfl_xor(d, off);
            // all lanes now hold the full dot
            float s = tanhf(d + bias[base + j]);
            float e = __expf(s);
            lsum += e;
            acc0.x += e * a[j][0].x; acc0.y += e * a[j][0].y;
            acc0.z += e * a[j][0].z; acc0.w += e * a[j][0].w;
            acc1.x += e * a[j][1].x; acc1.y += e * a[j][1].y;
            acc1.z += e * a[j][1].z; acc1.w += e * a[j][1].w;
            acc2.x += e * a[j][2].x; acc2.y += e * a[j][2].y;
            acc2.z += e * a[j][2].z; acc2.w += e * a[j][2].w;
            acc3.x += e * a[j][3].x; acc3.y += e * a[j][3].y;
            acc3.z += e * a[j][3].z; acc3.w += e * a[j][3].w;
        }
    }

    // combine 4 waves within the block via LDS
    __shared__ float lacc[4 * 1024];
    __shared__ float lls[4];
    float4* lacc4 = (float4*)lacc;
    lacc4[wv * 256 + lane]       = acc0;
    lacc4[wv * 256 + 64 + lane]  = acc1;
    lacc4[wv * 256 + 128 + lane] = acc2;
    lacc4[wv * 256 + 192 + lane] = acc3;
    if (lane == 0) lls[wv] = lsum;
    __syncthreads();

    const int tid = threadIdx.x;
    float4 o0 = lacc4[tid];
    float4 o1 = lacc4[256 + tid];
    float4 o2 = lacc4[512 + tid];
    float4 o3 = lacc4[768 + tid];
    float4 o;
    o.x = (o0.x + o1.x) + (o2.x + o3.x);
    o.y = (o0.y + o1.y) + (o2.y + o3.y);
    o.z = (o0.z + o1.z) + (o2.z + o3.z);
    o.w = (o0.w + o1.w) + (o2.w + o3.w);

    float* p = partials + (size_t)(b * C + c) * PSTR;
    if (tid == 0) p[0] = (lls[0] + lls[1]) + (lls[2] + lls[3]);
    ((float4*)(p + 8))[tid] = o;
}

__global__ __launch_bounds__(256) void combine_kernel(
    const float* __restrict__ partials, float* __restrict__ out, int C)
{
    const int b = blockIdx.x;
    const int tid = threadIdx.x;
    float L = 0.f;
    float4 o = {0.f,0.f,0.f,0.f};
    for (int c = 0; c < C; ++c) {
        const float* p = partials + (size_t)(b * C + c) * PSTR;
        L += p[0];
        float4 a = ((const float4*)(p + 8))[tid];
        o.x += a.x; o.y += a.y; o.z += a.z; o.w += a.w;
    }
    float inv = 1.f / L;
    float4 r; r.x = o.x * inv; r.y = o.y * inv; r.z = o.z * inv; r.w = o.w * inv;
    ((float4*)out)[b * 256 + tid] = r;
}

extern "C" void kernel_launch(void* const* d_in, const int* in_sizes, int n_in,
                              void* d_out, int out_size, void* d_ws, size_t ws_size,
                              hipStream_t stream) {
    const float* x    = (const float*)d_in[0];   // [B,T,D]
    const float* w    = (const float*)d_in[1];   // [D,1]
    const float* bias = (const float*)d_in[2];   // [T,1]
    float* out = (float*)d_out;

    int D = in_sizes[1];            // 1024
    int T = in_sizes[2];            // 2048
    int nrows = in_sizes[0] / D;    // B*T
    int B = nrows / T;              // 32

    // pick #chunks per batch: fit ws, keep rows/chunk a multiple of 16
    int C = 32;
    while (C > 1 && (size_t)B * C * PSTR * sizeof(float) > ws_size) C >>= 1;
    while (C > 1 && (T % (C * 16)) != 0) C >>= 1;

    float* partials = (float*)d_ws;

    fused_score_pool<<<dim3(C, B), 256, 0, stream>>>(x, w, bias, partials, T, C);
    combine_kernel<<<B, 256, 0, stream>>>(partials, out, C);
}